// Round 11
// baseline (81.471 us; speedup 1.0000x reference)
//
#include <hip/hip_runtime.h>

namespace {

constexpr int kB = 256;
constexpr int kS = 512;
constexpr int CHUNK  = 30;                        // useful frames per wave (32 lane-pairs, 2 overlap)
constexpr int NCHUNK = (kS + CHUNK - 1) / CHUNK;  // 18
constexpr int NSLOT  = 64;
constexpr int LROW   = 38;                        // LDS row stride (floats); 6 mod 32 -> mild aliasing only
constexpr int LWAVE  = 64 * LROW;                 // per-WG LDS floats (9728 B)

// pre-scaled loss weights (lambda / count); non-contact terms counted by BOTH parities (2x)
constexpr float BSf   = 131072.f;                 // kB*kS
constexpr float K_R1  = 5.0f / (2.f * BSf * 3.f);
constexpr float K_R2  = 5.0f / (2.f * BSf * 6.f);
constexpr float K_ROT = 1.0f / (2.f * BSf * 120.f);
constexpr float K_POS = 2.0f / (2.f * BSf * 66.f);
constexpr float K_VEL = 1.0f / (2.f * 256.f * 511.f * 66.f);
constexpr float K_SMO = 0.5f / (2.f * 256.f * 510.f * 66.f);
constexpr float K_FLO = 2.0f / (2.f * BSf * 2.f);
constexpr float K_CON = 2.0f / (256.f * 511.f * 2.f);   // even lanes only (no 2x)
constexpr float K_TIL = 1.0f / (2.f * BSf * 3.f);

__device__ __forceinline__ void cont6d(const float a[6], float R[3][3]) {
    float n1 = sqrtf(a[0]*a[0] + a[1]*a[1] + a[2]*a[2]);
    float i1 = 1.0f / fmaxf(n1, 1e-12f);
    float b1x = a[0]*i1, b1y = a[1]*i1, b1z = a[2]*i1;
    float dp  = b1x*a[3] + b1y*a[4] + b1z*a[5];
    float ux = a[3] - b1x*dp, uy = a[4] - b1y*dp, uz = a[5] - b1z*dp;
    float n2 = sqrtf(ux*ux + uy*uy + uz*uz);
    float i2 = 1.0f / fmaxf(n2, 1e-12f);
    float b2x = ux*i2, b2y = uy*i2, b2z = uz*i2;
    R[0][0] = b1x; R[1][0] = b1y; R[2][0] = b1z;
    R[0][1] = b2x; R[1][1] = b2y; R[2][1] = b2z;
    R[0][2] = b1y*b2z - b1z*b2y;
    R[1][2] = b1z*b2x - b1x*b2z;
    R[2][2] = b1x*b2y - b1y*b2x;
}

// T14 split staging: issue loads early (registers), ds_write late.
template<int C2, int FB>
__device__ __forceinline__ void stage_load(float2 (&st)[18],
                                           const float* __restrict__ pred,
                                           const float* __restrict__ targ,
                                           size_t rowbase, int s0, int lane) {
    constexpr int V = 32 * C2;           // float2 elements per tensor
    constexpr int R = (2 * V) / 64;      // V in {576,384} -> R in {18,12}
    #pragma unroll
    for (int r = 0; r < R; ++r) {
        int u = r * 64 + lane;
        int par2 = (u >= V) ? 1 : 0;
        int uu = u - par2 * V;
        int f = uu / C2;
        int c = uu - f * C2;
        int sf = s0 + f; sf = (sf < kS) ? sf : (kS - 1);
        const float* tp = par2 ? targ : pred;
        st[r] = *reinterpret_cast<const float2*>(tp + (rowbase + (size_t)sf) * 132 + FB + 2 * c);
    }
}

template<int C2>
__device__ __forceinline__ void stage_write(const float2 (&st)[18],
                                            float* __restrict__ ldsw, int lane) {
    constexpr int V = 32 * C2;
    constexpr int R = (2 * V) / 64;
    #pragma unroll
    for (int r = 0; r < R; ++r) {
        int u = r * 64 + lane;
        int par2 = (u >= V) ? 1 : 0;
        int uu = u - par2 * V;
        int f = uu / C2;
        int c = uu - f * C2;
        *reinterpret_cast<float2*>(ldsw + (2 * f + par2) * LROW + 2 * c) = st[r];
    }
}

__device__ __forceinline__ void read6(const float* __restrict__ row, int jj, float a[6]) {
    const float2* q = reinterpret_cast<const float2*>(row + 6 * jj);
    float2 x = q[0], y = q[1], z = q[2];
    a[0]=x.x; a[1]=x.y; a[2]=y.x; a[3]=y.y; a[4]=z.x; a[5]=z.y;
}

// One FK joint for this lane's skeleton. a = own 6 floats, ap = partner's
// (from LDS). Frame s+1 at lane+2, s+2 at lane+4. Squares parity-invariant.
template<bool NEED_R, bool SPINE_J, bool FOOT>
__device__ __forceinline__ void joint_step(
    const float a[6], const float ap[6], const float* __restrict__ off,
    const float Rp[3][3], const float pp[3],
    float Rn[3][3], float pn[3],
    float w_raw, float w_pos, float w_vel, float w_smo,
    float w_til, float w_flo, float w_con, float& s)
{
    float dsum = 0.f;
    #pragma unroll
    for (int k = 0; k < 6; ++k) { float d = a[k] - ap[k]; dsum += d*d; }
    s += w_raw * dsum;

    const float ox = off[0], oy = off[1], oz = off[2];
    #pragma unroll
    for (int r = 0; r < 3; ++r)
        pn[r] = pp[r] + Rp[r][0]*ox + Rp[r][1]*oy + Rp[r][2]*oz;

    if constexpr (NEED_R) {
        float Rl[3][3];
        cont6d(a, Rl);
        if constexpr (SPINE_J) {
            float t0 = Rl[0][1] - __shfl_xor(Rl[0][1], 1);
            float t1 = Rl[1][1] - __shfl_xor(Rl[1][1], 1);
            float t2 = Rl[2][1] - __shfl_xor(Rl[2][1], 1);
            s += w_til * (t0*t0 + t1*t1 + t2*t2);
        }
        #pragma unroll
        for (int r = 0; r < 3; ++r)
            #pragma unroll
            for (int c = 0; c < 3; ++c)
                Rn[r][c] = Rp[r][0]*Rl[0][c] + Rp[r][1]*Rl[1][c] + Rp[r][2]*Rl[2][c];
    }

    float d[3];
    #pragma unroll
    for (int r = 0; r < 3; ++r) d[r] = pn[r] - __shfl_xor(pn[r], 1);
    s += w_pos * (d[0]*d[0] + d[1]*d[1] + d[2]*d[2]);

    float va = 0.f, sa = 0.f;
    #pragma unroll
    for (int r = 0; r < 3; ++r) {
        float d1 = __shfl_down(d[r], 2);
        float d2 = __shfl_down(d[r], 4);
        float dv = d1 - d[r];            va += dv*dv;
        float ds = d2 - 2.f*d1 + d[r];   sa += ds*ds;
    }
    s += w_vel * va;
    s += w_smo * sa;

    if constexpr (FOOT) {
        s += w_flo * d[1]*d[1];
        float vx = __shfl_down(pn[0], 2) - pn[0];
        float vy = __shfl_down(pn[1], 2) - pn[1];
        float vz = __shfl_down(pn[2], 2) - pn[2];
        float gx = __shfl_xor(vx, 1);
        float gy = __shfl_xor(vy, 1);
        float gz = __shfl_xor(vz, 1);
        float planted = (gx*gx + gy*gy + gz*gz < 2.5e-5f) ? 1.f : 0.f;
        s += w_con * planted * sqrtf(vx*vx + vy*vy + vz*vz);
    }
}

// Single-wave WG (r10 frame, best: 78 us) + register-prefetch pipeline.
// NO occupancy hints (any VGPR cap <136 spills: r2/r4/r6/r8). Target VGPR
// ~168 <= 170 so residency stays 3 waves/SIMD (512/168 = 3.04).
__global__ __launch_bounds__(64)
void motion_loss_kernel(const float* __restrict__ pred,
                        const float* __restrict__ targ,
                        const float* __restrict__ offs,
                        float* __restrict__ acc)
{
    __shared__ float lds[LWAVE];

    const int lane = threadIdx.x;
    const int fid  = lane >> 1;         // frame-in-chunk 0..31
    const int par  = lane & 1;          // 0 = pred, 1 = targ

    const int cg    = blockIdx.x;                 // chunk id, 0..4607
    const int b     = cg / NCHUNK;
    const int chunk = cg - b * NCHUNK;
    const int s0    = chunk * CHUNK;
    const int s     = s0 + fid;
    const size_t rowbase = (size_t)b * kS;

    const float wf = (fid < CHUNK && s     < kS) ? 1.f : 0.f;
    const float wv = (fid < CHUNK && s + 1 < kS) ? 1.f : 0.f;
    const float wa = (fid < CHUNK && s + 2 < kS) ? 1.f : 0.f;
    const float wc = (par == 0) ? wv : 0.f;

    const float w_r1  = wf * K_R1,  w_r2  = wf * K_R2,  w_rot = wf * K_ROT;
    const float w_pos = wf * K_POS, w_til = wf * K_TIL, w_flo = wf * K_FLO;
    const float w_vel = wv * K_VEL, w_smo = wa * K_SMO, w_con = wc * K_CON;

    float* ldsw = lds;
    const float* ldsr = ldsw + lane * LROW;          // own row
    const float* ldsp = ldsw + (lane ^ 1) * LROW;    // partner row

    float loss = 0.f;
    float R1[3][3], R3[3][3], RA[3][3], RB[3][3];
    float p1[3], p3[3], pA[3], pB[3], pS[3];
    float2 st[18];

    #define JS(J, JJ, NR, SP, FT, RP, PP, RN, PN) { \
        float a_[6], ap_[6]; read6(ldsr, JJ, a_); read6(ldsp, JJ, ap_); \
        joint_step<NR, SP, FT>(a_, ap_, offs + (J)*3, RP, PP, RN, PN, \
                               w_rot, w_pos, w_vel, w_smo, w_til, w_flo, w_con, loss); }

    // ---- prologue: stage p0, then prefetch p1 into registers ----
    stage_load<18, 0>(st, pred, targ, rowbase, s0, lane);
    stage_write<18>(st, ldsw, lane);                 // vmcnt waits auto-inserted
    stage_load<18, 36>(st, pred, targ, rowbase, s0, lane);   // p1 in flight
    __builtin_amdgcn_sched_barrier(0);               // pin loads above compute

    // ---------------- phase 0: joints 0..5 ----------------
    { // joint 0: root channels 0..2; positions identically 0
        float d0 = ldsr[0] - ldsp[0];
        float d1 = ldsr[1] - ldsp[1];
        float d2 = ldsr[2] - ldsp[2];
        loss += w_r1 * (d0*d0 + d1*d1 + d2*d2);
    }
    { // joint 1: parent identity; pos = offs[1] for both (pos losses cancel)
        float a_[6], ap_[6];
        read6(ldsr, 1, a_); read6(ldsp, 1, ap_);
        float dsum = 0.f;
        #pragma unroll
        for (int k = 0; k < 6; ++k) { float d = a_[k] - ap_[k]; dsum += d*d; }
        loss += w_r2 * dsum;
        cont6d(a_, R1);
        p1[0] = offs[3]; p1[1] = offs[4]; p1[2] = offs[5];
    }
    JS( 2, 2, true , true , false, R1, p1, RA, pA);   // spine
    JS( 3, 3, true , false, false, RA, pA, R3, p3);
    JS( 4, 4, true , false, false, R3, p3, RA, pA);
    JS( 5, 5, false, false, false, RA, pA, RB, pS);   // leaf

    // ---------------- phase 1: joints 6..11 ----------------
    asm volatile("s_waitcnt lgkmcnt(0)" ::: "memory");       // p0 reads done (WAR)
    stage_write<18>(st, ldsw, lane);                          // p1 -> LDS
    stage_load<18, 72>(st, pred, targ, rowbase, s0, lane);    // prefetch p2
    __builtin_amdgcn_sched_barrier(0);
    JS( 6, 0, true , false, false, R3, p3, RA, pA);
    JS( 7, 1, true , false, false, RA, pA, RB, pB);
    JS( 8, 2, true , false, false, RB, pB, RA, pA);
    JS( 9, 3, false, false, false, RA, pA, RB, pS);   // leaf
    JS(10, 4, true , false, false, R3, p3, RB, pB);   // R3 dies
    JS(11, 5, true , false, false, RB, pB, RA, pA);

    // ---------------- phase 2: joints 12..17 ----------------
    asm volatile("s_waitcnt lgkmcnt(0)" ::: "memory");
    stage_write<18>(st, ldsw, lane);                          // p2 -> LDS
    stage_load<12, 108>(st, pred, targ, rowbase, s0, lane);   // prefetch p3
    __builtin_amdgcn_sched_barrier(0);
    JS(12, 0, true , false, false, RA, pA, RB, pB);
    JS(13, 1, false, false, false, RB, pB, RA, pS);   // leaf
    JS(14, 2, true , false, false, R1, p1, RA, pA);
    JS(15, 3, true , false, false, RA, pA, RB, pB);
    JS(16, 4, true , false, false, RB, pB, RA, pA);
    JS(17, 5, true , false, false, RA, pA, RB, pB);

    // ---------------- phase 3: joints 18..21 ----------------
    asm volatile("s_waitcnt lgkmcnt(0)" ::: "memory");
    stage_write<12>(st, ldsw, lane);                          // p3 -> LDS
    JS(18, 0, false, false, true , RB, pB, RA, pS);   // FOOT leaf
    JS(19, 1, true , false, false, R1, p1, RA, pA);   // R1 dies
    JS(20, 2, true , false, false, RA, pA, RB, pB);
    JS(21, 3, false, false, true , RB, pB, RA, pS);   // FOOT leaf
    #undef JS

    // wave butterfly reduce; one atomic per wave, spread over 64 slots
    float v = loss;
    #pragma unroll
    for (int o = 32; o > 0; o >>= 1) v += __shfl_xor(v, o);
    if (lane == 0) atomicAdd(&acc[cg & (NSLOT - 1)], v);
}

__global__ void finalize_kernel(const float* __restrict__ acc, float* __restrict__ out) {
    float v = acc[threadIdx.x];
    #pragma unroll
    for (int o = 32; o > 0; o >>= 1) v += __shfl_xor(v, o);
    if (threadIdx.x == 0) out[0] = v;
}

} // namespace

extern "C" void kernel_launch(void* const* d_in, const int* in_sizes, int n_in,
                              void* d_out, int out_size, void* d_ws, size_t ws_size,
                              hipStream_t stream) {
    const float* pred = (const float*)d_in[0];
    const float* targ = (const float*)d_in[1];
    const float* offs = (const float*)d_in[2];
    float* acc = (float*)d_ws;

    hipMemsetAsync(acc, 0, NSLOT * sizeof(float), stream);
    motion_loss_kernel<<<dim3(kB * NCHUNK), dim3(64), 0, stream>>>(pred, targ, offs, acc);
    finalize_kernel<<<1, 64, 0, stream>>>(acc, (float*)d_out);
}

// Round 12
// 69.747 us; speedup vs baseline: 1.1681x; 1.1681x over previous
//
#include <hip/hip_runtime.h>

namespace {

constexpr int kB = 256;
constexpr int kS = 512;
constexpr int CHUNK  = 30;                        // useful frames per wave (32 lane-pairs, 2 overlap)
constexpr int NCHUNK = (kS + CHUNK - 1) / CHUNK;  // 18
constexpr int NSLOT  = 64;
constexpr int LROW   = 38;                        // LDS row stride (floats)
constexpr int LWAVE  = 64 * LROW;                 // per-WG LDS floats (9728 B)

// lambda / count constants — used as INLINE LITERALS inside joint_step (zero
// register cost; K*term folds the literal into one v_mul). Non-contact terms
// counted by BOTH parities (2x in denominator).
constexpr float BSf   = 131072.f;                 // kB*kS
constexpr float K_R1  = 5.0f / (2.f * BSf * 3.f);
constexpr float K_R2  = 5.0f / (2.f * BSf * 6.f);
constexpr float K_ROT = 1.0f / (2.f * BSf * 120.f);
constexpr float K_POS = 2.0f / (2.f * BSf * 66.f);
constexpr float K_VEL = 1.0f / (2.f * 256.f * 511.f * 66.f);
constexpr float K_SMO = 0.5f / (2.f * 256.f * 510.f * 66.f);
constexpr float K_FLO = 2.0f / (2.f * BSf * 2.f);
constexpr float K_CON = 2.0f / (256.f * 511.f * 2.f);   // even lanes only (no 2x)
constexpr float K_TIL = 1.0f / (2.f * BSf * 3.f);

__device__ __forceinline__ void cont6d(const float a[6], float R[3][3]) {
    float n1 = sqrtf(a[0]*a[0] + a[1]*a[1] + a[2]*a[2]);
    float i1 = 1.0f / fmaxf(n1, 1e-12f);
    float b1x = a[0]*i1, b1y = a[1]*i1, b1z = a[2]*i1;
    float dp  = b1x*a[3] + b1y*a[4] + b1z*a[5];
    float ux = a[3] - b1x*dp, uy = a[4] - b1y*dp, uz = a[5] - b1z*dp;
    float n2 = sqrtf(ux*ux + uy*uy + uz*uz);
    float i2 = 1.0f / fmaxf(n2, 1e-12f);
    float b2x = ux*i2, b2y = uy*i2, b2z = uz*i2;
    R[0][0] = b1x; R[1][0] = b1y; R[2][0] = b1z;
    R[0][1] = b2x; R[1][1] = b2y; R[2][1] = b2z;
    R[0][2] = b1y*b2z - b1z*b2y;
    R[1][2] = b1z*b2x - b1x*b2z;
    R[2][2] = b1x*b2y - b1y*b2x;
}

// Fused coalesced global -> LDS stage (st dies inside the call; r10-proven).
template<int C2, int FB>
__device__ __forceinline__ void stage(const float* __restrict__ pred,
                                      const float* __restrict__ targ,
                                      size_t rowbase, int s0,
                                      float* __restrict__ ldsw, int lane) {
    constexpr int V = 32 * C2;           // float2 elements per tensor
    constexpr int R = (2 * V) / 64;      // V in {576,384} -> R in {18,12}
    float2 st[18];
    #pragma unroll
    for (int r = 0; r < R; ++r) {
        int u = r * 64 + lane;
        int par2 = (u >= V) ? 1 : 0;
        int uu = u - par2 * V;
        int f = uu / C2;
        int c = uu - f * C2;
        int sf = s0 + f; sf = (sf < kS) ? sf : (kS - 1);
        const float* tp = par2 ? targ : pred;
        st[r] = *reinterpret_cast<const float2*>(tp + (rowbase + (size_t)sf) * 132 + FB + 2 * c);
    }
    #pragma unroll
    for (int r = 0; r < R; ++r) {
        int u = r * 64 + lane;
        int par2 = (u >= V) ? 1 : 0;
        int uu = u - par2 * V;
        int f = uu / C2;
        int c = uu - f * C2;
        *reinterpret_cast<float2*>(ldsw + (2 * f + par2) * LROW + 2 * c) = st[r];
    }
}

__device__ __forceinline__ void read6(const float* __restrict__ row, int jj, float a[6]) {
    const float2* q = reinterpret_cast<const float2*>(row + 6 * jj);
    float2 x = q[0], y = q[1], z = q[2];
    a[0]=x.x; a[1]=x.y; a[2]=y.x; a[3]=y.y; a[4]=z.x; a[5]=z.y;
}

// One FK joint. Weights: only wf/wv/wa/par live registers; lambda/count
// factors are inline literals (K*term first, then *w — keeps K immediate).
template<bool NEED_R, bool SPINE_J, bool FOOT>
__device__ __forceinline__ void joint_step(
    const float a[6], const float ap[6], const float* __restrict__ off,
    const float Rp[3][3], const float pp[3],
    float Rn[3][3], float pn[3],
    float wf, float wv, float wa, int par, float& s)
{
    float dsum = 0.f;
    #pragma unroll
    for (int k = 0; k < 6; ++k) { float d = a[k] - ap[k]; dsum += d*d; }
    s += wf * (K_ROT * dsum);

    const float ox = off[0], oy = off[1], oz = off[2];
    #pragma unroll
    for (int r = 0; r < 3; ++r)
        pn[r] = pp[r] + Rp[r][0]*ox + Rp[r][1]*oy + Rp[r][2]*oz;

    if constexpr (NEED_R) {
        float Rl[3][3];
        cont6d(a, Rl);
        if constexpr (SPINE_J) {
            float t0 = Rl[0][1] - __shfl_xor(Rl[0][1], 1);
            float t1 = Rl[1][1] - __shfl_xor(Rl[1][1], 1);
            float t2 = Rl[2][1] - __shfl_xor(Rl[2][1], 1);
            s += wf * (K_TIL * (t0*t0 + t1*t1 + t2*t2));
        }
        #pragma unroll
        for (int r = 0; r < 3; ++r)
            #pragma unroll
            for (int c = 0; c < 3; ++c)
                Rn[r][c] = Rp[r][0]*Rl[0][c] + Rp[r][1]*Rl[1][c] + Rp[r][2]*Rl[2][c];
    }

    float d[3];
    #pragma unroll
    for (int r = 0; r < 3; ++r) d[r] = pn[r] - __shfl_xor(pn[r], 1);
    s += wf * (K_POS * (d[0]*d[0] + d[1]*d[1] + d[2]*d[2]));

    float va = 0.f, sa = 0.f;
    float v0 = 0.f;
    #pragma unroll
    for (int r = 0; r < 3; ++r) {
        float d1 = __shfl_down(d[r], 2);
        float d2 = __shfl_down(d[r], 4);
        float dv = d1 - d[r];            va += dv*dv;
        float ds = d2 - 2.f*d1 + d[r];   sa += ds*ds;
        if (r == 1) v0 = dv;             // (unused; keeps structure identical)
    }
    (void)v0;
    s += wv * (K_VEL * va);
    s += wa * (K_SMO * sa);

    if constexpr (FOOT) {
        s += wf * (K_FLO * (d[1]*d[1]));
        float vx = __shfl_down(pn[0], 2) - pn[0];
        float vy = __shfl_down(pn[1], 2) - pn[1];
        float vz = __shfl_down(pn[2], 2) - pn[2];
        float gx = __shfl_xor(vx, 1);
        float gy = __shfl_xor(vy, 1);
        float gz = __shfl_xor(vz, 1);
        float planted = (gx*gx + gy*gy + gz*gz < 2.5e-5f) ? 1.f : 0.f;
        float wc = (par == 0) ? wv : 0.f;         // rematerialized here (no live reg)
        s += wc * (K_CON * (planted * sqrtf(vx*vx + vy*vy + vz*vz)));
    }
}

// r10 frame (best clean run: 78 us, VGPR 132, 3 waves/SIMD). Source-level
// register shave targets <=128 VGPR -> 4 waves/SIMD (the 128-step from m69).
// NO occupancy hints (any compiler VGPR cap <136 spills: r2/r4/r6/r8).
__global__ __launch_bounds__(64)
void motion_loss_kernel(const float* __restrict__ pred,
                        const float* __restrict__ targ,
                        const float* __restrict__ offs,
                        float* __restrict__ acc)
{
    __shared__ float lds[LWAVE];

    const int lane = threadIdx.x;
    const int fid  = lane >> 1;         // frame-in-chunk 0..31
    const int par  = lane & 1;          // 0 = pred, 1 = targ

    const int cg    = blockIdx.x;                 // chunk id, 0..4607
    const int b     = cg / NCHUNK;
    const int chunk = cg - b * NCHUNK;
    const int s0    = chunk * CHUNK;
    const int s     = s0 + fid;
    const size_t rowbase = (size_t)b * kS;

    const float wf = (fid < CHUNK && s     < kS) ? 1.f : 0.f;
    const float wv = (fid < CHUNK && s + 1 < kS) ? 1.f : 0.f;
    const float wa = (fid < CHUNK && s + 2 < kS) ? 1.f : 0.f;

    float* ldsw = lds;
    const float* ldsr = ldsw + lane * LROW;          // own row
    const float* ldsp = ldsw + (lane ^ 1) * LROW;    // partner row

    float loss = 0.f;
    float R1[3][3], R3[3][3], RA[3][3], RB[3][3];
    float p1[3], p3[3], pA[3], pB[3], pS[3];

    #define JS(J, JJ, NR, SP, FT, RP, PP, RN, PN) { \
        float a_[6], ap_[6]; read6(ldsr, JJ, a_); read6(ldsp, JJ, ap_); \
        joint_step<NR, SP, FT>(a_, ap_, offs + (J)*3, RP, PP, RN, PN, \
                               wf, wv, wa, par, loss); }

    // ---------------- phase 0: joints 0..5 (floats 0..36) ----------------
    stage<18, 0>(pred, targ, rowbase, s0, ldsw, lane);

    { // joint 0: root channels 0..2; positions identically 0
        float d0 = ldsr[0] - ldsp[0];
        float d1 = ldsr[1] - ldsp[1];
        float d2 = ldsr[2] - ldsp[2];
        loss += wf * (K_R1 * (d0*d0 + d1*d1 + d2*d2));
    }
    { // joint 1: parent identity; pos = offs[1] for both (pos losses cancel)
        float a_[6], ap_[6];
        read6(ldsr, 1, a_); read6(ldsp, 1, ap_);
        float dsum = 0.f;
        #pragma unroll
        for (int k = 0; k < 6; ++k) { float d = a_[k] - ap_[k]; dsum += d*d; }
        loss += wf * (K_R2 * dsum);
        cont6d(a_, R1);
        p1[0] = offs[3]; p1[1] = offs[4]; p1[2] = offs[5];
    }
    JS( 2, 2, true , true , false, R1, p1, RA, pA);   // spine
    JS( 3, 3, true , false, false, RA, pA, R3, p3);
    JS( 4, 4, true , false, false, R3, p3, RA, pA);
    JS( 5, 5, false, false, false, RA, pA, RB, pS);   // leaf

    // ---------------- phase 1: joints 6..11 (floats 36..72) ----------------
    asm volatile("s_waitcnt lgkmcnt(0)" ::: "memory");
    stage<18, 36>(pred, targ, rowbase, s0, ldsw, lane);
    JS( 6, 0, true , false, false, R3, p3, RA, pA);
    JS( 7, 1, true , false, false, RA, pA, RB, pB);
    JS( 8, 2, true , false, false, RB, pB, RA, pA);
    JS( 9, 3, false, false, false, RA, pA, RB, pS);   // leaf
    JS(10, 4, true , false, false, R3, p3, RB, pB);   // R3 dies
    JS(11, 5, true , false, false, RB, pB, RA, pA);

    // ---------------- phase 2: joints 12..17 (floats 72..108) ----------------
    asm volatile("s_waitcnt lgkmcnt(0)" ::: "memory");
    stage<18, 72>(pred, targ, rowbase, s0, ldsw, lane);
    JS(12, 0, true , false, false, RA, pA, RB, pB);
    JS(13, 1, false, false, false, RB, pB, RA, pS);   // leaf
    JS(14, 2, true , false, false, R1, p1, RA, pA);
    JS(15, 3, true , false, false, RA, pA, RB, pB);
    JS(16, 4, true , false, false, RB, pB, RA, pA);
    JS(17, 5, true , false, false, RA, pA, RB, pB);

    // ---------------- phase 3: joints 18..21 (floats 108..132) ----------------
    asm volatile("s_waitcnt lgkmcnt(0)" ::: "memory");
    stage<12, 108>(pred, targ, rowbase, s0, ldsw, lane);
    JS(18, 0, false, false, true , RB, pB, RA, pS);   // FOOT leaf
    JS(19, 1, true , false, false, R1, p1, RA, pA);   // R1 dies
    JS(20, 2, true , false, false, RA, pA, RB, pB);
    JS(21, 3, false, false, true , RB, pB, RA, pS);   // FOOT leaf
    #undef JS

    // wave butterfly reduce; one atomic per wave, spread over 64 slots
    float v = loss;
    #pragma unroll
    for (int o = 32; o > 0; o >>= 1) v += __shfl_xor(v, o);
    if (lane == 0) atomicAdd(&acc[cg & (NSLOT - 1)], v);
}

__global__ void finalize_kernel(const float* __restrict__ acc, float* __restrict__ out) {
    float v = acc[threadIdx.x];
    #pragma unroll
    for (int o = 32; o > 0; o >>= 1) v += __shfl_xor(v, o);
    if (threadIdx.x == 0) out[0] = v;
}

} // namespace

extern "C" void kernel_launch(void* const* d_in, const int* in_sizes, int n_in,
                              void* d_out, int out_size, void* d_ws, size_t ws_size,
                              hipStream_t stream) {
    const float* pred = (const float*)d_in[0];
    const float* targ = (const float*)d_in[1];
    const float* offs = (const float*)d_in[2];
    float* acc = (float*)d_ws;

    hipMemsetAsync(acc, 0, NSLOT * sizeof(float), stream);
    motion_loss_kernel<<<dim3(kB * NCHUNK), dim3(64), 0, stream>>>(pred, targ, offs, acc);
    finalize_kernel<<<1, 64, 0, stream>>>(acc, (float*)d_out);
}